// Round 10
// baseline (109.446 us; speedup 1.0000x reference)
//
#include <hip/hip_runtime.h>
#include <math.h>

#define B_  4
#define P_  512
#define K_  4
#define H_  200
#define W_  336
#define A_  14
#define PS_ 56
#define SCALE_ 0.25f
#define HW_    (H_ * W_)
#define RROWB_ (PS_ * K_ * 4)    // bytes per smR row (= 896)
#define SW_    74                // smF row stride in 8B elems
#define SROWB_ (SW_ * 8)         // 592 bytes per smF row
#define NROWS_ 73                // max staged rows

#if __has_builtin(__builtin_amdgcn_exp2f)
#define EXP2F(x) __builtin_amdgcn_exp2f(x)
#else
#define EXP2F(x) exp2f(x)
#endif

typedef unsigned long long ull;

// bf16 round-to-nearest-even
static __device__ __forceinline__ unsigned f2bf(float x) {
    unsigned u = __float_as_uint(x);
    return (u + 0x7fffu + ((u >> 16) & 1u)) >> 16;
}
static __device__ __forceinline__ unsigned pk2(float a, float b) {
    return f2bf(a) | (f2bf(b) << 16);
}
#define LOF(u) __uint_as_float((u) << 16)
#define HIF(u) __uint_as_float((u) & 0xffff0000u)

// ---- Pass 1: bases [B,K,H,W] -> ws [B,H,W] = bf16 {k0|k1, k2|k3} (8B/pixel) ----
__global__ __launch_bounds__(256) void transpose_bases(
    const float* __restrict__ bases, ull* __restrict__ ws)
{
    const int i = blockIdx.x * 256 + threadIdx.x;    // over B*H*W = 268800
    if (i >= B_ * HW_) return;
    const int b = i / HW_;
    const int r = i - b * HW_;
    const float* src = bases + (size_t)b * (K_ * HW_) + r;
    const unsigned lo = pk2(src[0 * HW_], src[1 * HW_]);
    const unsigned hi = pk2(src[2 * HW_], src[3 * HW_]);
    ws[i] = (ull)lo | ((ull)hi << 32);
}

// ---- Pass 2: main blender, RoI rectangle staged in LDS ----
__global__ __launch_bounds__(448) void blender_kernel(
    const ull* __restrict__ wsb,       // [B,H,W] bf16-packed bases
    const float* __restrict__ boxes,   // [B,P,4]
    const float* __restrict__ attn,    // [B,P,K,A,A]
    float* __restrict__ out)           // [B,P,PS,PS]
{
    const int tid = threadIdx.x;       // 448 threads, 7 waves
    const int bp  = blockIdx.x;
    const int b   = bp >> 9;           // / 512

    __shared__ ull    smF[NROWS_ * SW_];   // staged RoI rect, 43,216 B
    __shared__ float  smR[A_ * PS_ * K_];  // x-interp attn*log2e, [ay][px][k]
    __shared__ float4 smX[PS_];            // {asint(j0*8), wl, wh, -}
    __shared__ float4 smY[PS_];            // {asint(r0*SROWB), asint(dr*SROWB), wy0, wy1}
    __shared__ float2 smAY[PS_];           // {asint(iy0*RROWB_), ty}

    // ---- box params (every thread; scalar-cached loads) ----
    const float* bx = boxes + (size_t)bp * 4;
    const float x1s = bx[0] * SCALE_, y1s = bx[1] * SCALE_;
    const float x2s = bx[2] * SCALE_, y2s = bx[3] * SCALE_;
    const float bwf = fmaxf(x2s - x1s, 1.0f) * (1.0f / PS_);
    const float bhf = fmaxf(y2s - y1s, 1.0f) * (1.0f / PS_);

    int xLo = (int)fminf(fmaxf(x1s + 0.5f * bwf, 0.0f), (float)(W_ - 1));
    int yLo = (int)fminf(fmaxf(y1s + 0.5f * bhf, 0.0f), (float)(H_ - 1));
    int xHi = min(W_ - 1, (int)fminf(fmaxf(x1s + 55.5f * bwf, 0.0f), (float)(W_ - 1)) + 1);
    int yHi = min(H_ - 1, (int)fminf(fmaxf(y1s + 55.5f * bhf, 0.0f), (float)(H_ - 1)) + 1);
    xHi = min(xHi, xLo + 72);
    yHi = min(yHi, yLo + 72);
    const int nCol = xHi - xLo + 2;        // +1 dup col for x+1 at right edge (<= 74)
    const int nRow = yHi - yLo + 1;        // <= 73
    const int cmax = W_ - 1 - xLo;         // staging col clamp

    // ---- Phase A1: stage RoI rect (coalesced 8B/lane from L2-resident wsb) ----
    {
        const ull* src = wsb + (size_t)b * HW_ + (size_t)yLo * W_ + xLo;
        for (int j = tid; j < NROWS_ * SW_; j += 448) {
            const int r = j / SW_;         // compile-time divisor
            const int c = j - r * SW_;
            if (r < nRow && c < nCol)
                smF[j] = src[(size_t)r * W_ + min(c, cmax)];
        }
    }

    // ---- Phase A2: separable tables ----
    const float rr = 13.0f / 55.0f;        // (A-1)/(PS-1)
    if (tid < PS_) {                       // x-side
        const int px = tid;
        const float sx = x1s + (px + 0.5f) * bwf;
        const float vx = (sx > -1.0f && sx < (float)W_) ? 1.0f : 0.0f;
        const float cx = fminf(fmaxf(sx, 0.0f), (float)(W_ - 1));
        const int   x0 = (int)cx;
        const float lx = cx - (float)x0;
        const int   j0 = min(max(x0 - xLo, 0), nCol - 2);
        float4 v;
        v.x = __int_as_float(j0 * 8);
        v.y = (1.0f - lx) * vx;
        v.z = lx * vx;
        v.w = 0.0f;
        smX[px] = v;
    } else if (tid >= 64 && tid < 64 + PS_) {  // y-side
        const int py = tid - 64;
        const float sy = y1s + (py + 0.5f) * bhf;
        const float vy = (sy > -1.0f && sy < (float)H_) ? 1.0f : 0.0f;
        const float cy = fminf(fmaxf(sy, 0.0f), (float)(H_ - 1));
        const int   y0 = (int)cy;
        const int   y1i = min(y0 + 1, H_ - 1);
        const float ly = cy - (float)y0;
        const int   r0 = min(max(y0 - yLo, 0), nRow - 1);
        const int   r1 = min(max(y1i - yLo, 0), nRow - 1);
        float4 v;
        v.x = __int_as_float(r0 * SROWB_);
        v.y = __int_as_float((r1 - r0) * SROWB_);
        v.z = (1.0f - ly) * vy;
        v.w = ly * vy;
        smY[py] = v;
        const float srcy = (float)py * rr;
        const int iy0 = min((int)srcy, A_ - 2);
        float2 a;
        a.x = __int_as_float(iy0 * RROWB_);
        a.y = srcy - (float)iy0;
        smAY[py] = a;
    }

    // ---- Phase A3: x-interp attn (direct from global) -> smR, pre-scaled ----
    const float LOG2E = 1.4426950408889634f;
    const float* ap = attn + (size_t)bp * (K_ * A_ * A_);
    for (int i = tid; i < K_ * A_ * PS_; i += 448) {   // 7 iters
        const int k  = i / (A_ * PS_);
        const int r1 = i - k * (A_ * PS_);
        const int ay = r1 / PS_;
        const int px = r1 - ay * PS_;
        const float srcx = (float)px * rr;
        const int ix0 = min((int)srcx, A_ - 2);
        const float tx = srcx - (float)ix0;
        const float* t = ap + k * (A_ * A_) + ay * A_ + ix0;
        smR[(ay * PS_ + px) * K_ + k] = (t[0] + tx * (t[1] - t[0])) * LOG2E;
    }
    __syncthreads();

    // ---- Phase B: main loop — 7 px/thread, all gathers from LDS ----
    float* outp = out + (size_t)bp * (PS_ * PS_);
    const int px  = tid % PS_;
    const int py0 = tid / PS_;                 // 0..7

    const float4 X = smX[px];                  // once per thread
    const int   xb8 = __float_as_int(X.x);
    const float wl = X.y, wh = X.z;
    const char* smFc = (const char*)smF;
    const char* smRbase = (const char*)smR + (px << 4);

    #pragma unroll
    for (int t = 0; t < 7; ++t) {
        const int py = py0 + 8 * t;
        const float4 Y  = smY[py];
        const float2 AY = smAY[py];
        const int o0 = __float_as_int(Y.x) + xb8;
        const int o1 = o0 + __float_as_int(Y.y);
        const float wy0 = Y.z, wy1 = Y.w;
        const float ty  = AY.y;

        const ull* p0 = (const ull*)(smFc + o0);   // row y0: x0, x0+1
        const ull  f00 = p0[0], f01 = p0[1];       // ds_read2_b64
        const ull* p1 = (const ull*)(smFc + o1);   // row y1
        const ull  f10 = p1[0], f11 = p1[1];

        const unsigned u00l = (unsigned)f00, u00h = (unsigned)(f00 >> 32);
        const unsigned u01l = (unsigned)f01, u01h = (unsigned)(f01 >> 32);
        const unsigned u10l = (unsigned)f10, u10h = (unsigned)(f10 >> 32);
        const unsigned u11l = (unsigned)f11, u11h = (unsigned)(f11 >> 32);

        // x-lerp then y-lerp, 4-wide over k (bf16 lo/hi unpack is free)
        const float r0a = fmaf(LOF(u01l), wh, LOF(u00l) * wl);
        const float r0b = fmaf(HIF(u01l), wh, HIF(u00l) * wl);
        const float r0c = fmaf(LOF(u01h), wh, LOF(u00h) * wl);
        const float r0d = fmaf(HIF(u01h), wh, HIF(u00h) * wl);
        const float r1a = fmaf(LOF(u11l), wh, LOF(u10l) * wl);
        const float r1b = fmaf(HIF(u11l), wh, HIF(u10l) * wl);
        const float r1c = fmaf(LOF(u11h), wh, LOF(u10h) * wl);
        const float r1d = fmaf(HIF(u11h), wh, HIF(u10h) * wl);
        const float v0 = fmaf(r1a, wy1, r0a * wy0);
        const float v1 = fmaf(r1b, wy1, r0b * wy0);
        const float v2 = fmaf(r1c, wy1, r0c * wy0);
        const float v3 = fmaf(r1d, wy1, r0d * wy0);

        const float4 a0v = *(const float4*)(smRbase + __float_as_int(AY.x));
        const float4 a1v = *(const float4*)(smRbase + __float_as_int(AY.x) + RROWB_);
        const float e0 = EXP2F(fmaf(ty, a1v.x - a0v.x, a0v.x));
        const float e1 = EXP2F(fmaf(ty, a1v.y - a0v.y, a0v.y));
        const float e2 = EXP2F(fmaf(ty, a1v.z - a0v.z, a0v.z));
        const float e3 = EXP2F(fmaf(ty, a1v.w - a0v.w, a0v.w));

        const float s = (e0 + e1) + (e2 + e3);
        float acc = e0 * v0;
        acc = fmaf(e1, v1, acc);
        acc = fmaf(e2, v2, acc);
        acc = fmaf(e3, v3, acc);

        __builtin_nontemporal_store(acc * __builtin_amdgcn_rcpf(s),
                                    outp + tid + 448 * t);
    }
}

extern "C" void kernel_launch(void* const* d_in, const int* in_sizes, int n_in,
                              void* d_out, int out_size, void* d_ws, size_t ws_size,
                              hipStream_t stream) {
    const float* bases = (const float*)d_in[0];  // [B,K,H,W]
    const float* boxes = (const float*)d_in[1];  // [B,P,4]
    const float* attn  = (const float*)d_in[2];  // [B,P,K,A,A]
    float* out = (float*)d_out;                  // [B,P,PS,PS]
    ull* wsb = (ull*)d_ws;                       // 268800 * 8 B = 2.15 MB

    transpose_bases<<<dim3((B_ * HW_ + 255) / 256), dim3(256), 0, stream>>>(bases, wsb);
    blender_kernel<<<dim3(B_ * P_), dim3(448), 0, stream>>>(wsb, boxes, attn, out);
}

// Round 12
// 88.695 us; speedup vs baseline: 1.2340x; 1.2340x over previous
//
#include <hip/hip_runtime.h>
#include <math.h>

#define B_  4
#define P_  512
#define K_  4
#define H_  200
#define W_  336
#define A_  14
#define PS_ 56
#define SCALE_ 0.25f
#define HW_    (H_ * W_)
#define PXB_   16                // bytes per ws pixel
#define ROWB_  (W_ * PXB_)       // 5376
#define PLB_   (HW_ * PXB_)      // bytes per (b) plane
#define RROWB_ (PS_ * K_ * 4)    // bytes per smR row (= 896)

#if __has_builtin(__builtin_amdgcn_exp2f)
#define EXP2F(x) __builtin_amdgcn_exp2f(x)
#else
#define EXP2F(x) exp2f(x)
#endif

typedef _Float16 h2 __attribute__((ext_vector_type(2)));

// pack two floats to f16x2 (RTZ) and return raw 32-bit
static __device__ __forceinline__ unsigned pkrtz_u(float a, float b) {
    auto h = __builtin_amdgcn_cvt_pkrtz(a, b);
    union { decltype(h) h; unsigned u; } c; c.h = h; return c.u;
}
static __device__ __forceinline__ h2 u2h(unsigned u) {
    union { unsigned u; h2 h; } c; c.u = u; return c.h;
}
static __device__ __forceinline__ float dot2(h2 a, h2 b, float c) {
#if __has_builtin(__builtin_amdgcn_fdot2)
    return __builtin_amdgcn_fdot2(a, b, c, false);
#else
    return (float)a.x * (float)b.x + ((float)a.y * (float)b.y + c);
#endif
}
static __device__ __forceinline__ uint4 ld16(const char* p) {
    uint4 q;
    __builtin_memcpy(&q, (const char*)__builtin_assume_aligned(p, 16), 16);
    return q;
}

// ---- Pass 1: bases [B,K,H,W] -> ws [B,H,W] = f16 {k:(x,x+1)} x4 (16B/pixel) ----
__global__ __launch_bounds__(256) void transpose_bases(
    const float* __restrict__ bases, uint4* __restrict__ ws)
{
    const int i = blockIdx.x * 256 + threadIdx.x;    // over B*H*W = 268800
    if (i >= B_ * HW_) return;
    const int b = i / HW_;
    const int r = i - b * HW_;
    const int x = r % W_;
    const int dn = (x < W_ - 1) ? 1 : 0;             // duplicate last column
    const float* src = bases + (size_t)b * (K_ * HW_) + r;
    uint4 w;
    w.x = pkrtz_u(src[0 * HW_], src[0 * HW_ + dn]);
    w.y = pkrtz_u(src[1 * HW_], src[1 * HW_ + dn]);
    w.z = pkrtz_u(src[2 * HW_], src[2 * HW_ + dn]);
    w.w = pkrtz_u(src[3 * HW_], src[3 * HW_ + dn]);
    ws[i] = w;
}

// ---- Pass 2: main blender ----
__global__ __launch_bounds__(448) void blender_kernel(
    const uint4* __restrict__ wsb,     // [B,H,W] f16 pair-duplicated bases
    const float* __restrict__ boxes,   // [B,P,4]
    const float* __restrict__ attn,    // [B,P,K,A,A]
    float* __restrict__ out)           // [B,P,PS,PS]
{
    const int tid = threadIdx.x;       // 448 threads, 7 waves
    const int bp  = blockIdx.x;
    const int b   = bp >> 9;           // / 512

    __shared__ float  smTile[K_ * A_ * A_];    // raw attn tile (784 f)
    __shared__ float  smR[A_ * PS_ * K_];      // x-interp attn*log2e, [ay][px][k]
    __shared__ float4 smX[PS_];                // {asint(x0*16), asuint(wx h2), -, -}
    __shared__ float4 smY[PS_];                // {asint(y0*ROWB), asint(dy*ROWB), wy00 h2, wy11 h2}
    __shared__ float2 smAY[PS_];               // {asint(iy0*RROWB_), ty}

    // ---- stage attn tile ----
    const float* ap = attn + (size_t)bp * (K_ * A_ * A_);
    for (int i = tid; i < K_ * A_ * A_; i += 448)
        smTile[i] = __builtin_nontemporal_load(ap + i);

    // ---- separable tables ----
    const float* bx = boxes + (size_t)bp * 4;
    const float rr = 13.0f / 55.0f;            // (A-1)/(PS-1)

    if (tid < PS_) {                           // x-side
        const int px = tid;
        const float x1 = bx[0] * SCALE_;
        const float x2 = bx[2] * SCALE_;
        const float bw = fmaxf(x2 - x1, 1.0f) * (1.0f / PS_);
        const float sx = x1 + (px + 0.5f) * bw;
        const float vx = (sx > -1.0f && sx < (float)W_) ? 1.0f : 0.0f;
        const float cx = fminf(fmaxf(sx, 0.0f), (float)(W_ - 1));
        const int   x0 = (int)cx;
        const float lx = cx - (float)x0;       // x0==W-1 -> lx==0, dup col absorbs
        float4 v;
        v.x = __int_as_float(x0 * PXB_);
        v.y = __uint_as_float(pkrtz_u((1.0f - lx) * vx, lx * vx));
        v.z = 0.0f;
        v.w = 0.0f;
        smX[px] = v;
    } else if (tid >= 64 && tid < 64 + PS_) {  // y-side
        const int py = tid - 64;
        const float y1 = bx[1] * SCALE_;
        const float y2 = bx[3] * SCALE_;
        const float bh = fmaxf(y2 - y1, 1.0f) * (1.0f / PS_);
        const float sy = y1 + (py + 0.5f) * bh;
        const float vy = (sy > -1.0f && sy < (float)H_) ? 1.0f : 0.0f;
        const float cy = fminf(fmaxf(sy, 0.0f), (float)(H_ - 1));
        const int   y0 = (int)cy;
        const int   y1i = min(y0 + 1, H_ - 1);
        const float ly = cy - (float)y0;
        const float wy0 = (1.0f - ly) * vy;
        const float wy1 = ly * vy;
        float4 v;
        v.x = __int_as_float(y0 * ROWB_);
        v.y = __int_as_float((y1i - y0) * ROWB_);
        v.z = __uint_as_float(pkrtz_u(wy0, wy0));
        v.w = __uint_as_float(pkrtz_u(wy1, wy1));
        smY[py] = v;
        const float srcy = (float)py * rr;
        const int iy0 = min((int)srcy, A_ - 2);
        float2 a;
        a.x = __int_as_float(iy0 * RROWB_);
        a.y = srcy - (float)iy0;
        smAY[py] = a;
    }
    __syncthreads();

    // ---- x-interp attn -> smR[ay][px][k], pre-scaled by log2(e) ----
    const float LOG2E = 1.4426950408889634f;
    for (int i = tid; i < K_ * A_ * PS_; i += 448) {
        const int k  = i / (A_ * PS_);
        const int r1 = i - k * (A_ * PS_);
        const int ay = r1 / PS_;
        const int px = r1 - ay * PS_;
        const float srcx = (float)px * rr;
        const int ix0 = min((int)srcx, A_ - 2);
        const float tx = srcx - (float)ix0;
        const float* t = smTile + k * (A_ * A_) + ay * A_ + ix0;
        smR[(ay * PS_ + px) * K_ + k] = (t[0] + tx * (t[1] - t[0])) * LOG2E;
    }
    __syncthreads();

    // ---- main loop: px fixed per thread; 7 rows per thread; 2-slot pipeline ----
    const char* fb = (const char*)wsb + (size_t)b * PLB_;
    float* outp = out + (size_t)bp * (PS_ * PS_);

    const int px  = tid % PS_;
    const int py0 = tid / PS_;                 // 0..7

    const float4 X = smX[px];                  // once per thread
    const unsigned xb = (unsigned)__float_as_int(X.x);
    const h2 wx = u2h(__float_as_uint(X.y));
    const char* smRbase = (const char*)smR + (px << 4);

    struct PState {
        uint4 q0, q1;
        unsigned wy00u, wy11u;
        float ty;
        int   ayo;
    };

    auto issue = [&](int t, PState& S) {
        const int py = py0 + 8 * t;
        const float4 Y  = smY[py];
        const float2 AY = smAY[py];
        const unsigned o0 = (unsigned)__float_as_int(Y.x) + xb;
        const unsigned o1 = o0 + (unsigned)__float_as_int(Y.y);
        S.q0 = ld16(fb + o0);                  // (y0: k0..3 × {x,x+1}) f16
        S.q1 = ld16(fb + o1);                  // (y1: ...)
        S.wy00u = __float_as_uint(Y.z);
        S.wy11u = __float_as_uint(Y.w);
        S.ty = AY.y; S.ayo = __float_as_int(AY.x);
    };

    auto compute = [&](const PState& S) -> float {
        const h2 wxy0 = wx * u2h(S.wy00u);     // v_pk_mul_f16
        const h2 wxy1 = wx * u2h(S.wy11u);
        // full bilinear per k: 2 chained v_dot2_f32_f16
        const float v0 = dot2(u2h(S.q1.x), wxy1, dot2(u2h(S.q0.x), wxy0, 0.0f));
        const float v1 = dot2(u2h(S.q1.y), wxy1, dot2(u2h(S.q0.y), wxy0, 0.0f));
        const float v2 = dot2(u2h(S.q1.z), wxy1, dot2(u2h(S.q0.z), wxy0, 0.0f));
        const float v3 = dot2(u2h(S.q1.w), wxy1, dot2(u2h(S.q0.w), wxy0, 0.0f));

        const float ty = S.ty;
        const float4 a0v = *(const float4*)(smRbase + S.ayo);
        const float4 a1v = *(const float4*)(smRbase + S.ayo + RROWB_);
        const float e0 = EXP2F(fmaf(ty, a1v.x - a0v.x, a0v.x));
        const float e1 = EXP2F(fmaf(ty, a1v.y - a0v.y, a0v.y));
        const float e2 = EXP2F(fmaf(ty, a1v.z - a0v.z, a0v.z));
        const float e3 = EXP2F(fmaf(ty, a1v.w - a0v.w, a0v.w));

        const float s = (e0 + e1) + (e2 + e3);
        float acc = e0 * v0;
        acc = fmaf(e1, v1, acc);
        acc = fmaf(e2, v2, acc);
        acc = fmaf(e3, v3, acc);
        return acc * __builtin_amdgcn_rcpf(s);
    };

    PState SA, SB;
    issue(0, SA);
    #pragma unroll
    for (int g = 0; g < 6; g += 2) {
        issue(g + 1, SB);
        __builtin_nontemporal_store(compute(SA), outp + tid + 448 * g);
        issue(g + 2, SA);
        __builtin_nontemporal_store(compute(SB), outp + tid + 448 * (g + 1));
    }
    __builtin_nontemporal_store(compute(SA), outp + tid + 448 * 6);
}

extern "C" void kernel_launch(void* const* d_in, const int* in_sizes, int n_in,
                              void* d_out, int out_size, void* d_ws, size_t ws_size,
                              hipStream_t stream) {
    const float* bases = (const float*)d_in[0];  // [B,K,H,W]
    const float* boxes = (const float*)d_in[1];  // [B,P,4]
    const float* attn  = (const float*)d_in[2];  // [B,P,K,A,A]
    float* out = (float*)d_out;                  // [B,P,PS,PS]
    uint4* wsb = (uint4*)d_ws;                   // 268800 * 16 B = 4.3 MB scratch

    transpose_bases<<<dim3((B_ * HW_ + 255) / 256), dim3(256), 0, stream>>>(bases, wsb);
    blender_kernel<<<dim3(B_ * P_), dim3(448), 0, stream>>>(wsb, boxes, attn, out);
}

// Round 13
// 86.537 us; speedup vs baseline: 1.2647x; 1.0249x over previous
//
#include <hip/hip_runtime.h>
#include <math.h>

#define B_  4
#define P_  512
#define K_  4
#define H_  200
#define W_  336
#define A_  14
#define PS_ 56
#define SCALE_ 0.25f
#define HW_    (H_ * W_)
#define PXB_   16                // bytes per ws pixel
#define ROWB_  (W_ * PXB_)       // 5376
#define PLB_   (HW_ * PXB_)      // bytes per (b) plane
#define RROWB_ (PS_ * K_ * 4)    // bytes per smR row (= 896)

#if __has_builtin(__builtin_amdgcn_exp2f)
#define EXP2F(x) __builtin_amdgcn_exp2f(x)
#else
#define EXP2F(x) exp2f(x)
#endif

typedef _Float16 h2 __attribute__((ext_vector_type(2)));

static __device__ __forceinline__ unsigned pkrtz_u(float a, float b) {
    auto h = __builtin_amdgcn_cvt_pkrtz(a, b);
    union { decltype(h) h; unsigned u; } c; c.h = h; return c.u;
}
static __device__ __forceinline__ h2 u2h(unsigned u) {
    union { unsigned u; h2 h; } c; c.u = u; return c.h;
}
static __device__ __forceinline__ float dot2(h2 a, h2 b, float c) {
#if __has_builtin(__builtin_amdgcn_fdot2)
    return __builtin_amdgcn_fdot2(a, b, c, false);
#else
    return (float)a.x * (float)b.x + ((float)a.y * (float)b.y + c);
#endif
}
static __device__ __forceinline__ uint4 ld16(const char* p) {
    uint4 q;
    __builtin_memcpy(&q, (const char*)__builtin_assume_aligned(p, 16), 16);
    return q;
}

// ---- Pass 1: bases [B,K,H,W] -> ws [B,H,W] = f16 {k:(x,x+1)} x4 (16B/pixel) ----
__global__ __launch_bounds__(256) void transpose_bases(
    const float* __restrict__ bases, uint4* __restrict__ ws)
{
    const int i = blockIdx.x * 256 + threadIdx.x;    // over B*H*W = 268800
    if (i >= B_ * HW_) return;
    const int b = i / HW_;
    const int r = i - b * HW_;
    const int x = r % W_;
    const int dn = (x < W_ - 1) ? 1 : 0;             // duplicate last column
    const float* src = bases + (size_t)b * (K_ * HW_) + r;
    uint4 w;
    w.x = pkrtz_u(src[0 * HW_], src[0 * HW_ + dn]);
    w.y = pkrtz_u(src[1 * HW_], src[1 * HW_ + dn]);
    w.z = pkrtz_u(src[2 * HW_], src[2 * HW_ + dn]);
    w.w = pkrtz_u(src[3 * HW_], src[3 * HW_ + dn]);
    ws[i] = w;
}

// ---- Pass 2: main blender — 256 thr/block, 8 blocks/CU, single dispatch round ----
__global__ __launch_bounds__(256, 8) void blender_kernel(
    const uint4* __restrict__ wsb,     // [B,H,W] f16 pair-duplicated bases
    const float* __restrict__ boxes,   // [B,P,4]
    const float* __restrict__ attn,    // [B,P,K,A,A]
    float* __restrict__ out)           // [B,P,PS,PS]
{
    const int tid = threadIdx.x;       // 256 threads, 4 waves
    const int bp  = blockIdx.x;
    const int b   = bp >> 9;           // / 512

    __shared__ float  smTile[K_ * A_ * A_];    // raw attn tile (784 f)
    __shared__ float  smR[A_ * PS_ * K_];      // x-interp attn*log2e, [ay][px][k]
    __shared__ float4 smX[PS_];                // {asint(x0*16), asuint(wx h2), -, -}
    __shared__ float4 smY[PS_];                // {asint(y0*ROWB), asint(dy*ROWB), wy00 h2, wy11 h2}
    __shared__ float2 smAY[PS_];               // {asint(iy0*RROWB_), ty}

    // ---- stage attn tile ----
    const float* ap = attn + (size_t)bp * (K_ * A_ * A_);
    for (int i = tid; i < K_ * A_ * A_; i += 256)
        smTile[i] = __builtin_nontemporal_load(ap + i);

    // ---- separable tables ----
    const float* bx = boxes + (size_t)bp * 4;
    const float rr = 13.0f / 55.0f;            // (A-1)/(PS-1)

    if (tid < PS_) {                           // x-side
        const int px = tid;
        const float x1 = bx[0] * SCALE_;
        const float x2 = bx[2] * SCALE_;
        const float bw = fmaxf(x2 - x1, 1.0f) * (1.0f / PS_);
        const float sx = x1 + (px + 0.5f) * bw;
        const float vx = (sx > -1.0f && sx < (float)W_) ? 1.0f : 0.0f;
        const float cx = fminf(fmaxf(sx, 0.0f), (float)(W_ - 1));
        const int   x0 = (int)cx;
        const float lx = cx - (float)x0;       // x0==W-1 -> lx==0, dup col absorbs
        float4 v;
        v.x = __int_as_float(x0 * PXB_);
        v.y = __uint_as_float(pkrtz_u((1.0f - lx) * vx, lx * vx));
        v.z = 0.0f;
        v.w = 0.0f;
        smX[px] = v;
    } else if (tid >= 64 && tid < 64 + PS_) {  // y-side
        const int py = tid - 64;
        const float y1 = bx[1] * SCALE_;
        const float y2 = bx[3] * SCALE_;
        const float bh = fmaxf(y2 - y1, 1.0f) * (1.0f / PS_);
        const float sy = y1 + (py + 0.5f) * bh;
        const float vy = (sy > -1.0f && sy < (float)H_) ? 1.0f : 0.0f;
        const float cy = fminf(fmaxf(sy, 0.0f), (float)(H_ - 1));
        const int   y0 = (int)cy;
        const int   y1i = min(y0 + 1, H_ - 1);
        const float ly = cy - (float)y0;
        const float wy0 = (1.0f - ly) * vy;
        const float wy1 = ly * vy;
        float4 v;
        v.x = __int_as_float(y0 * ROWB_);
        v.y = __int_as_float((y1i - y0) * ROWB_);
        v.z = __uint_as_float(pkrtz_u(wy0, wy0));
        v.w = __uint_as_float(pkrtz_u(wy1, wy1));
        smY[py] = v;
        const float srcy = (float)py * rr;
        const int iy0 = min((int)srcy, A_ - 2);
        float2 a;
        a.x = __int_as_float(iy0 * RROWB_);
        a.y = srcy - (float)iy0;
        smAY[py] = a;
    }
    __syncthreads();

    // ---- x-interp attn -> smR[ay][px][k], pre-scaled by log2(e) ----
    const float LOG2E = 1.4426950408889634f;
    for (int i = tid; i < K_ * A_ * PS_; i += 256) {
        const int k  = i / (A_ * PS_);
        const int r1 = i - k * (A_ * PS_);
        const int ay = r1 / PS_;
        const int px = r1 - ay * PS_;
        const float srcx = (float)px * rr;
        const int ix0 = min((int)srcx, A_ - 2);
        const float tx = srcx - (float)ix0;
        const float* t = smTile + k * (A_ * A_) + ay * A_ + ix0;
        smR[(ay * PS_ + px) * K_ + k] = (t[0] + tx * (t[1] - t[0])) * LOG2E;
    }
    __syncthreads();

    // ---- main loop: idx = tid + 256*t, t = 0..11 (+64 tail); 2-slot pipeline ----
    const char* fb = (const char*)wsb + (size_t)b * PLB_;
    float* outp = out + (size_t)bp * (PS_ * PS_);
    const char* smRc = (const char*)smR;

    // initial px/py for idx = tid  (py = idx/56 via magic, px = rem)
    int py = (int)(((unsigned)tid * 37450u) >> 21);
    int px = tid - py * PS_;

    struct PState {
        uint4 q0, q1;
        unsigned wxu, wy00u, wy11u;
        float ty;
        int   ayo, pxo;
    };

    // issue for current (px,py), then advance (px,py) by 256 linear (py+=4, px+=32)
    auto issue = [&](PState& S) {
        const int pyc = min(py, PS_ - 1);      // clamp: speculative tail prefetch
        const float4 X  = smX[px];
        const float4 Y  = smY[pyc];
        const float2 AY = smAY[pyc];
        const unsigned o0 = (unsigned)__float_as_int(Y.x) + (unsigned)__float_as_int(X.x);
        const unsigned o1 = o0 + (unsigned)__float_as_int(Y.y);
        S.q0 = ld16(fb + o0);
        S.q1 = ld16(fb + o1);
        S.wxu   = __float_as_uint(X.y);
        S.wy00u = __float_as_uint(Y.z);
        S.wy11u = __float_as_uint(Y.w);
        S.ty  = AY.y;
        S.ayo = __float_as_int(AY.x);
        S.pxo = px << 4;
        px += 32; py += 4;
        if (px >= PS_) { px -= PS_; py += 1; }
    };

    auto compute = [&](const PState& S) -> float {
        const h2 wx   = u2h(S.wxu);
        const h2 wxy0 = wx * u2h(S.wy00u);     // v_pk_mul_f16
        const h2 wxy1 = wx * u2h(S.wy11u);
        const float v0 = dot2(u2h(S.q1.x), wxy1, dot2(u2h(S.q0.x), wxy0, 0.0f));
        const float v1 = dot2(u2h(S.q1.y), wxy1, dot2(u2h(S.q0.y), wxy0, 0.0f));
        const float v2 = dot2(u2h(S.q1.z), wxy1, dot2(u2h(S.q0.z), wxy0, 0.0f));
        const float v3 = dot2(u2h(S.q1.w), wxy1, dot2(u2h(S.q0.w), wxy0, 0.0f));

        const char* rb = smRc + S.pxo + S.ayo;
        const float4 a0v = *(const float4*)(rb);
        const float4 a1v = *(const float4*)(rb + RROWB_);
        const float ty = S.ty;
        const float e0 = EXP2F(fmaf(ty, a1v.x - a0v.x, a0v.x));
        const float e1 = EXP2F(fmaf(ty, a1v.y - a0v.y, a0v.y));
        const float e2 = EXP2F(fmaf(ty, a1v.z - a0v.z, a0v.z));
        const float e3 = EXP2F(fmaf(ty, a1v.w - a0v.w, a0v.w));

        const float s = (e0 + e1) + (e2 + e3);
        float acc = e0 * v0;
        acc = fmaf(e1, v1, acc);
        acc = fmaf(e2, v2, acc);
        acc = fmaf(e3, v3, acc);
        return acc * __builtin_amdgcn_rcpf(s);
    };

    PState SA, SB;
    issue(SA);
    #pragma unroll
    for (int g = 0; g < 12; g += 2) {
        issue(SB);
        __builtin_nontemporal_store(compute(SA), outp + tid + 256 * g);
        issue(SA);                              // g=10 -> prefetches tail (clamped)
        __builtin_nontemporal_store(compute(SB), outp + tid + 256 * (g + 1));
    }
    if (tid < 64)                               // tail: idx = 3072 + tid
        __builtin_nontemporal_store(compute(SA), outp + tid + 256 * 12);
}

extern "C" void kernel_launch(void* const* d_in, const int* in_sizes, int n_in,
                              void* d_out, int out_size, void* d_ws, size_t ws_size,
                              hipStream_t stream) {
    const float* bases = (const float*)d_in[0];  // [B,K,H,W]
    const float* boxes = (const float*)d_in[1];  // [B,P,4]
    const float* attn  = (const float*)d_in[2];  // [B,P,K,A,A]
    float* out = (float*)d_out;                  // [B,P,PS,PS]
    uint4* wsb = (uint4*)d_ws;                   // 268800 * 16 B = 4.3 MB scratch

    transpose_bases<<<dim3((B_ * HW_ + 255) / 256), dim3(256), 0, stream>>>(bases, wsb);
    blender_kernel<<<dim3(B_ * P_), dim3(256), 0, stream>>>(wsb, boxes, attn, out);
}

// Round 14
// 86.492 us; speedup vs baseline: 1.2654x; 1.0005x over previous
//
#include <hip/hip_runtime.h>
#include <math.h>

#define B_  4
#define P_  512
#define K_  4
#define H_  200
#define W_  336
#define A_  14
#define PS_ 56
#define SCALE_ 0.25f
#define HW_    (H_ * W_)
#define PXB_   16                // bytes per ws pixel
#define ROWB_  (W_ * PXB_)       // 5376
#define PLB_   (HW_ * PXB_)      // bytes per (b) plane
#define RROWB_ (PS_ * K_ * 4)    // bytes per smR row (= 896)

#if __has_builtin(__builtin_amdgcn_exp2f)
#define EXP2F(x) __builtin_amdgcn_exp2f(x)
#else
#define EXP2F(x) exp2f(x)
#endif

typedef _Float16 h2 __attribute__((ext_vector_type(2)));

static __device__ __forceinline__ unsigned pkrtz_u(float a, float b) {
    auto h = __builtin_amdgcn_cvt_pkrtz(a, b);
    union { decltype(h) h; unsigned u; } c; c.h = h; return c.u;
}
static __device__ __forceinline__ h2 u2h(unsigned u) {
    union { unsigned u; h2 h; } c; c.u = u; return c.h;
}
static __device__ __forceinline__ float dot2(h2 a, h2 b, float c) {
#if __has_builtin(__builtin_amdgcn_fdot2)
    return __builtin_amdgcn_fdot2(a, b, c, false);
#else
    return (float)a.x * (float)b.x + ((float)a.y * (float)b.y + c);
#endif
}
static __device__ __forceinline__ uint4 ld16(const char* p) {
    uint4 q;
    __builtin_memcpy(&q, (const char*)__builtin_assume_aligned(p, 16), 16);
    return q;
}

// ---- Pass 1: bases [B,K,H,W] -> ws [B,H,W] = f16 {k:(x,x+1)} x4 (16B/pixel) ----
__global__ __launch_bounds__(256) void transpose_bases(
    const float* __restrict__ bases, uint4* __restrict__ ws)
{
    const int i = blockIdx.x * 256 + threadIdx.x;    // over B*H*W = 268800
    if (i >= B_ * HW_) return;
    const int b = i / HW_;
    const int r = i - b * HW_;
    const int x = r % W_;
    const int dn = (x < W_ - 1) ? 1 : 0;             // duplicate last column
    const float* src = bases + (size_t)b * (K_ * HW_) + r;
    uint4 w;
    w.x = pkrtz_u(src[0 * HW_], src[0 * HW_ + dn]);
    w.y = pkrtz_u(src[1 * HW_], src[1 * HW_ + dn]);
    w.z = pkrtz_u(src[2 * HW_], src[2 * HW_ + dn]);
    w.w = pkrtz_u(src[3 * HW_], src[3 * HW_ + dn]);
    ws[i] = w;
}

// ---- Pass 2: main blender — 256 thr/block, 8 blocks/CU, single dispatch round ----
__global__ __launch_bounds__(256, 8) void blender_kernel(
    const uint4* __restrict__ wsb,     // [B,H,W] f16 pair-duplicated bases
    const float* __restrict__ boxes,   // [B,P,4]
    const float* __restrict__ attn,    // [B,P,K,A,A]
    float* __restrict__ out)           // [B,P,PS,PS]
{
    const int tid = threadIdx.x;       // 256 threads, 4 waves
    const int bp  = blockIdx.x;
    const int b   = bp >> 9;           // / 512

    __shared__ float  smTile[K_ * A_ * A_];    // raw attn tile (784 f)
    __shared__ float  smR[A_ * PS_ * K_];      // x-interp attn*log2e, [ay][px][k]
    __shared__ float4 smX[PS_];                // {asint(x0*16), asuint(wx h2), -, -}
    __shared__ float4 smY[PS_];                // {asint(y0*ROWB), o_dy|(ayo<<16), pk(wy0,wy1), ty}

    // ---- stage attn tile ----
    const float* ap = attn + (size_t)bp * (K_ * A_ * A_);
    for (int i = tid; i < K_ * A_ * A_; i += 256)
        smTile[i] = __builtin_nontemporal_load(ap + i);

    // ---- separable tables ----
    const float* bx = boxes + (size_t)bp * 4;
    const float rr = 13.0f / 55.0f;            // (A-1)/(PS-1)

    if (tid < PS_) {                           // x-side
        const int px = tid;
        const float x1 = bx[0] * SCALE_;
        const float x2 = bx[2] * SCALE_;
        const float bw = fmaxf(x2 - x1, 1.0f) * (1.0f / PS_);
        const float sx = x1 + (px + 0.5f) * bw;
        const float vx = (sx > -1.0f && sx < (float)W_) ? 1.0f : 0.0f;
        const float cx = fminf(fmaxf(sx, 0.0f), (float)(W_ - 1));
        const int   x0 = (int)cx;
        const float lx = cx - (float)x0;       // x0==W-1 -> lx==0, dup col absorbs
        float4 v;
        v.x = __int_as_float(x0 * PXB_);
        v.y = __uint_as_float(pkrtz_u((1.0f - lx) * vx, lx * vx));
        v.z = 0.0f;
        v.w = 0.0f;
        smX[px] = v;
    } else if (tid >= 64 && tid < 64 + PS_) {  // y-side
        const int py = tid - 64;
        const float y1 = bx[1] * SCALE_;
        const float y2 = bx[3] * SCALE_;
        const float bh = fmaxf(y2 - y1, 1.0f) * (1.0f / PS_);
        const float sy = y1 + (py + 0.5f) * bh;
        const float vy = (sy > -1.0f && sy < (float)H_) ? 1.0f : 0.0f;
        const float cy = fminf(fmaxf(sy, 0.0f), (float)(H_ - 1));
        const int   y0 = (int)cy;
        const int   y1i = min(y0 + 1, H_ - 1);
        const float ly = cy - (float)y0;
        const float wy0 = (1.0f - ly) * vy;
        const float wy1 = ly * vy;
        const float srcy = (float)py * rr;
        const int iy0 = min((int)srcy, A_ - 2);
        const unsigned odp = (unsigned)((y1i - y0) * ROWB_)     // 13 bits
                           | ((unsigned)(iy0 * RROWB_) << 16);  // 14 bits
        float4 v;
        v.x = __int_as_float(y0 * ROWB_);
        v.y = __uint_as_float(odp);
        v.z = __uint_as_float(pkrtz_u(wy0, wy1));
        v.w = srcy - (float)iy0;               // ty, fp32
        smY[py] = v;
    }
    __syncthreads();

    // ---- x-interp attn -> smR[ay][px][k], pre-scaled by log2(e) ----
    const float LOG2E = 1.4426950408889634f;
    for (int i = tid; i < K_ * A_ * PS_; i += 256) {
        const int k  = i / (A_ * PS_);
        const int r1 = i - k * (A_ * PS_);
        const int ay = r1 / PS_;
        const int px = r1 - ay * PS_;
        const float srcx = (float)px * rr;
        const int ix0 = min((int)srcx, A_ - 2);
        const float tx = srcx - (float)ix0;
        const float* t = smTile + k * (A_ * A_) + ay * A_ + ix0;
        smR[(ay * PS_ + px) * K_ + k] = (t[0] + tx * (t[1] - t[0])) * LOG2E;
    }
    __syncthreads();

    // ---- main loop: idx = tid + 256*t, t = 0..11 (+64 tail); 2-slot pipeline ----
    const char* fb = (const char*)wsb + (size_t)b * PLB_;
    float* outp = out + (size_t)bp * (PS_ * PS_);
    const char* smRc = (const char*)smR;

    // initial px/py for idx = tid  (py = idx/56 via magic, px = rem)
    int py = (int)(((unsigned)tid * 37450u) >> 21);
    int px = tid - py * PS_;

    struct PState {
        uint4 q0, q1;
        unsigned wxu, wyu;
        float ty;
        int   ayo, pxo;
    };

    // issue for current (px,py), then advance (px,py) by 256 linear
    auto issue = [&](PState& S) {
        const int pyc = min(py, PS_ - 1);      // clamp: speculative tail prefetch
        const float4 X = smX[px];
        const float4 Y = smY[pyc];
        const unsigned w1 = __float_as_uint(Y.y);
        const unsigned o0 = (unsigned)__float_as_int(Y.x) + (unsigned)__float_as_int(X.x);
        const unsigned o1 = o0 + (w1 & 0xffffu);
        S.q0 = ld16(fb + o0);
        S.q1 = ld16(fb + o1);
        S.wxu = __float_as_uint(X.y);
        S.wyu = __float_as_uint(Y.z);
        S.ty  = Y.w;
        S.ayo = (int)(w1 >> 16);
        S.pxo = px << 4;
        px += 32; py += 4;
        if (px >= PS_) { px -= PS_; py += 1; }
    };

    auto compute = [&](const PState& S) -> float {
        const h2 wx  = u2h(S.wxu);
        const h2 wyp = u2h(S.wyu);             // {wy0, wy1}
        const h2 wy0b = {wyp.x, wyp.x};        // op_sel broadcast
        const h2 wy1b = {wyp.y, wyp.y};
        const h2 wxy0 = wx * wy0b;             // v_pk_mul_f16
        const h2 wxy1 = wx * wy1b;
        const float v0 = dot2(u2h(S.q1.x), wxy1, dot2(u2h(S.q0.x), wxy0, 0.0f));
        const float v1 = dot2(u2h(S.q1.y), wxy1, dot2(u2h(S.q0.y), wxy0, 0.0f));
        const float v2 = dot2(u2h(S.q1.z), wxy1, dot2(u2h(S.q0.z), wxy0, 0.0f));
        const float v3 = dot2(u2h(S.q1.w), wxy1, dot2(u2h(S.q0.w), wxy0, 0.0f));

        const char* rb = smRc + S.pxo + S.ayo;
        const float4 a0v = *(const float4*)(rb);
        const float4 a1v = *(const float4*)(rb + RROWB_);
        const float ty = S.ty;
        const float e0 = EXP2F(fmaf(ty, a1v.x - a0v.x, a0v.x));
        const float e1 = EXP2F(fmaf(ty, a1v.y - a0v.y, a0v.y));
        const float e2 = EXP2F(fmaf(ty, a1v.z - a0v.z, a0v.z));
        const float e3 = EXP2F(fmaf(ty, a1v.w - a0v.w, a0v.w));

        const float s = (e0 + e1) + (e2 + e3);
        float acc = e0 * v0;
        acc = fmaf(e1, v1, acc);
        acc = fmaf(e2, v2, acc);
        acc = fmaf(e3, v3, acc);
        return acc * __builtin_amdgcn_rcpf(s);
    };

    PState SA, SB;
    issue(SA);
    #pragma unroll
    for (int g = 0; g < 12; g += 2) {
        issue(SB);
        __builtin_nontemporal_store(compute(SA), outp + tid + 256 * g);
        issue(SA);                              // g=10 -> prefetches tail (clamped)
        __builtin_nontemporal_store(compute(SB), outp + tid + 256 * (g + 1));
    }
    if (tid < 64)                               // tail: idx = 3072 + tid
        __builtin_nontemporal_store(compute(SA), outp + tid + 256 * 12);
}

extern "C" void kernel_launch(void* const* d_in, const int* in_sizes, int n_in,
                              void* d_out, int out_size, void* d_ws, size_t ws_size,
                              hipStream_t stream) {
    const float* bases = (const float*)d_in[0];  // [B,K,H,W]
    const float* boxes = (const float*)d_in[1];  // [B,P,4]
    const float* attn  = (const float*)d_in[2];  // [B,P,K,A,A]
    float* out = (float*)d_out;                  // [B,P,PS,PS]
    uint4* wsb = (uint4*)d_ws;                   // 268800 * 16 B = 4.3 MB scratch

    transpose_bases<<<dim3((B_ * HW_ + 255) / 256), dim3(256), 0, stream>>>(bases, wsb);
    blender_kernel<<<dim3(B_ * P_), dim3(256), 0, stream>>>(wsb, boxes, attn, out);
}